// Round 1
// baseline (181.376 us; speedup 1.0000x reference)
//
#include <hip/hip_runtime.h>

// HighOrderActivation: B=2048, G=512, K=4, D=32
// out[b,g,d] = sum_k coef[b,g,k] * params[g, idx[b,g,k], d]
// where coef/idx derive from ascending sort of X[b,g,:4].

#define NB 2048
#define NG 512
#define NPAIRS (NB * NG)

// branchless compare-exchange tracking original index
#define CSWAP(a, ia, b, ib)                                         \
    do {                                                            \
        const bool sw_ = (b) < (a);                                 \
        const float ta_ = sw_ ? (b) : (a);                          \
        const float tb_ = sw_ ? (a) : (b);                          \
        const int tia_ = sw_ ? (ib) : (ia);                         \
        const int tib_ = sw_ ? (ia) : (ib);                         \
        (a) = ta_; (b) = tb_; (ia) = tia_; (ib) = tib_;             \
    } while (0)

__global__ __launch_bounds__(256) void hoa_kernel(
    const float* __restrict__ X,      // (B, G, 4)
    const float* __restrict__ P,      // (G, 16, 32)
    float* __restrict__ out)          // (B, G, 32)
{
    const int t = threadIdx.x;
    const int d4 = t & 7;                    // which float4 of the 32-wide d dim
    int pair = blockIdx.x * 32 + (t >> 3);   // 32 pairs per 256-thread block
    const int stride = gridDim.x * 32;

    for (; pair < NPAIRS; pair += stride) {
        const int g = pair & (NG - 1);

        // broadcast load of the 4 X values for this (b,g)
        const float4 xv = *reinterpret_cast<const float4*>(X + ((size_t)pair << 2));
        float a0 = xv.x, a1 = xv.y, a2 = xv.z, a3 = xv.w;
        int i0 = 0, i1 = 1, i2 = 2, i3 = 3;

        // 4-element sorting network: (0,1),(2,3),(0,2),(1,3),(1,2)
        CSWAP(a0, i0, a1, i1);
        CSWAP(a2, i2, a3, i3);
        CSWAP(a0, i0, a2, i2);
        CSWAP(a1, i1, a3, i3);
        CSWAP(a1, i1, a2, i2);

        // masks of top-(4-k) element indices
        const int m1 = 15 ^ (1 << i0);
        const int m2 = (1 << i2) | (1 << i3);
        const int m3 = 1 << i3;

        const float c0 = a0;
        const float c1 = a1 - a0;
        const float c2 = a2 - a1;
        const float c3 = a3 - a2;

        const float* Pg = P + ((size_t)g << 9);   // g * 16 * 32
        const int dofs = d4 << 2;                 // this thread's 4 d's

        const float4 p0 = *reinterpret_cast<const float4*>(Pg + (15 << 5) + dofs);
        const float4 p1 = *reinterpret_cast<const float4*>(Pg + (m1 << 5) + dofs);
        const float4 p2 = *reinterpret_cast<const float4*>(Pg + (m2 << 5) + dofs);
        const float4 p3 = *reinterpret_cast<const float4*>(Pg + (m3 << 5) + dofs);

        float4 r;
        r.x = c0 * p0.x + c1 * p1.x + c2 * p2.x + c3 * p3.x;
        r.y = c0 * p0.y + c1 * p1.y + c2 * p2.y + c3 * p3.y;
        r.z = c0 * p0.z + c1 * p1.z + c2 * p2.z + c3 * p3.z;
        r.w = c0 * p0.w + c1 * p1.w + c2 * p2.w + c3 * p3.w;

        *reinterpret_cast<float4*>(out + ((size_t)pair << 5) + dofs) = r;
    }
}

extern "C" void kernel_launch(void* const* d_in, const int* in_sizes, int n_in,
                              void* d_out, int out_size, void* d_ws, size_t ws_size,
                              hipStream_t stream) {
    const float* X = (const float*)d_in[0];     // (2048, 512, 4) f32
    const float* P = (const float*)d_in[1];     // (512, 16, 32) f32
    float* out = (float*)d_out;                 // (2048, 512, 32) f32

    hoa_kernel<<<dim3(2048), dim3(256), 0, stream>>>(X, P, out);
}

// Round 9
// 174.518 us; speedup vs baseline: 1.0393x; 1.0393x over previous
//
#include <hip/hip_runtime.h>

// HighOrderActivation: B=2048, G=512, K=4, D=32
// out[b,g,d] = sum_k coef[b,g,k] * params[g, idx[b,g,k], d]
// coef/idx derive from ascending sort of X[b,g,:4] (sorting network; ties
// carry zero coefficients so unstable sort is exact).
//
// Memory-bound: out 128 MiB (stream write), X 16 MiB (stream read),
// params 1 MiB (L2-resident gather). Roofline ~23 us @ 6.3 TB/s.
// Non-temporal hints on the streamed tensors keep params hot in L2.
// NOTE: __builtin_nontemporal_* requires a NATIVE vector type (clang
// ext_vector_type), not HIP's float4 class — hence vf4 below.

#define NB 2048
#define NG 512
#define NPAIRS (NB * NG)

typedef float vf4 __attribute__((ext_vector_type(4)));

#define CSWAP(a, ia, b, ib)                                         \
    do {                                                            \
        const bool sw_ = (b) < (a);                                 \
        const float ta_ = sw_ ? (b) : (a);                          \
        const float tb_ = sw_ ? (a) : (b);                          \
        const int tia_ = sw_ ? (ib) : (ia);                         \
        const int tib_ = sw_ ? (ia) : (ib);                         \
        (a) = ta_; (b) = tb_; (ia) = tia_; (ib) = tib_;             \
    } while (0)

__global__ __launch_bounds__(256) void hoa_kernel(
    const float* __restrict__ X,      // (B, G, 4)
    const float* __restrict__ P,      // (G, 16, 32)
    float* __restrict__ out)          // (B, G, 32)
{
    const int t = threadIdx.x;
    const int d4 = t & 7;                        // which float4 of the 32-wide d
    const int pair = blockIdx.x * 32 + (t >> 3); // 32 pairs per 256-thread block
    const int g = pair & (NG - 1);

    // stream-once read of the 4 X values for this (b,g)
    const vf4 xv = __builtin_nontemporal_load(
        reinterpret_cast<const vf4*>(X + ((size_t)pair << 2)));
    float a0 = xv.x, a1 = xv.y, a2 = xv.z, a3 = xv.w;
    int i0 = 0, i1 = 1, i2 = 2, i3 = 3;

    // 4-element sorting network: (0,1),(2,3),(0,2),(1,3),(1,2)
    CSWAP(a0, i0, a1, i1);
    CSWAP(a2, i2, a3, i3);
    CSWAP(a0, i0, a2, i2);
    CSWAP(a1, i1, a3, i3);
    CSWAP(a1, i1, a2, i2);

    // masks of top-(4-k) element indices
    const int m1 = 15 ^ (1 << i0);
    const int m2 = (1 << i2) | (1 << i3);
    const int m3 = 1 << i3;

    const float c0 = a0;
    const float c1 = a1 - a0;
    const float c2 = a2 - a1;
    const float c3 = a3 - a2;

    const float* Pg = P + ((size_t)g << 9);   // g * 16 * 32
    const int dofs = d4 << 2;                 // this thread's 4 d's

    const vf4 p0 = *reinterpret_cast<const vf4*>(Pg + (15 << 5) + dofs);
    const vf4 p1 = *reinterpret_cast<const vf4*>(Pg + (m1 << 5) + dofs);
    const vf4 p2 = *reinterpret_cast<const vf4*>(Pg + (m2 << 5) + dofs);
    const vf4 p3 = *reinterpret_cast<const vf4*>(Pg + (m3 << 5) + dofs);

    vf4 r;
    r.x = c0 * p0.x + c1 * p1.x + c2 * p2.x + c3 * p3.x;
    r.y = c0 * p0.y + c1 * p1.y + c2 * p2.y + c3 * p3.y;
    r.z = c0 * p0.z + c1 * p1.z + c2 * p2.z + c3 * p3.z;
    r.w = c0 * p0.w + c1 * p1.w + c2 * p2.w + c3 * p3.w;

    // stream-once write
    __builtin_nontemporal_store(
        r, reinterpret_cast<vf4*>(out + ((size_t)pair << 5) + dofs));
}

extern "C" void kernel_launch(void* const* d_in, const int* in_sizes, int n_in,
                              void* d_out, int out_size, void* d_ws, size_t ws_size,
                              hipStream_t stream) {
    const float* X = (const float*)d_in[0];     // (2048, 512, 4) f32
    const float* P = (const float*)d_in[1];     // (512, 16, 32) f32
    float* out = (float*)d_out;                 // (2048, 512, 32) f32

    // exact grid: NPAIRS * 8 threads / 256 = 32768 blocks
    hoa_kernel<<<dim3(NPAIRS / 32), dim3(256), 0, stream>>>(X, P, out);
}